// Round 1
// baseline (579.218 us; speedup 1.0000x reference)
//
#include <hip/hip_runtime.h>
#include <hip/hip_bf16.h>

// Sizes fixed by the reference
#define HV   128
#define HT   17
#define DIMD 290        // 2*(HV+HT)
#define KP   320        // K padded to 10*32 for mfma 16x16x32
#define LDSP 328        // LDS row pitch (bf16 elems) to break bank aliasing
#define OO   640        // 5*HV
#define RT   64         // rows per block
#define KN   8          // number of types

typedef unsigned short u16;
typedef __attribute__((ext_vector_type(8))) short short8v;
typedef __attribute__((ext_vector_type(4))) float f32x4;

__device__ __forceinline__ u16 f2bf(float x) {
    unsigned u = __float_as_uint(x);
    u = (u + 0x7FFFu + ((u >> 16) & 1u)) >> 16;   // RNE
    return (u16)u;
}
__device__ __forceinline__ float sigf(float x) {
    return 1.0f / (1.0f + __expf(-x));
}

// ws header layout (ints): [0..7] counts, [8..15] scatter cursors,
// [16..24] blkStart prefix (blkStart[8] = total row-blocks)

__global__ void hist_k(const int* __restrict__ pt, int* __restrict__ hdr, int N) {
    __shared__ int c[KN];
    if (threadIdx.x < KN) c[threadIdx.x] = 0;
    __syncthreads();
    int n = blockIdx.x * 256 + threadIdx.x;
    if (n < N) atomicAdd(&c[pt[n]], 1);
    __syncthreads();
    if (threadIdx.x < KN && c[threadIdx.x]) atomicAdd(&hdr[threadIdx.x], c[threadIdx.x]);
}

__global__ void prefix_k(int* __restrict__ hdr) {
    if (threadIdx.x == 0 && blockIdx.x == 0) {
        int acc = 0;
        hdr[16] = 0;
        for (int k = 0; k < KN; ++k) {
            acc += (hdr[k] + RT - 1) / RT;
            hdr[17 + k] = acc;
        }
    }
}

__global__ void scatter_k(const int* __restrict__ pt, int* __restrict__ hdr,
                          int* __restrict__ idxbuf, int N) {
    __shared__ int c[KN], base[KN];
    if (threadIdx.x < KN) c[threadIdx.x] = 0;
    __syncthreads();
    int n = blockIdx.x * 256 + threadIdx.x;
    int k = 0, my = 0;
    if (n < N) { k = pt[n]; my = atomicAdd(&c[k], 1); }
    __syncthreads();
    if (threadIdx.x < KN)
        base[threadIdx.x] = c[threadIdx.x] ? atomicAdd(&hdr[8 + threadIdx.x], c[threadIdx.x]) : 0;
    __syncthreads();
    if (n < N) idxbuf[hdr[16 + k] * RT + base[k] + my] = n;
}

// W (K,O,290) fp32 -> Wbf (K,O,320) bf16 with column permutation:
// x' layout = [h_l 0..128 | h_r 128..256 | t_l 256..273 | t_r 273..290 | 0 pad]
__global__ void wconv_k(const float* __restrict__ W, u16* __restrict__ Wbf) {
    int k = blockIdx.y;
    int idx = blockIdx.x * 256 + threadIdx.x;
    if (idx >= OO * KP) return;
    int o = idx / KP, d = idx % KP;
    int src;
    if (d < 256)      src = (d < 128) ? d : d + 17;   // h_l / h_r (orig h_r at 145)
    else if (d < 273) src = d - 128;                  // t_l (orig at 128)
    else if (d < 290) src = d;                        // t_r (orig at 273)
    else              src = -1;                       // pad
    float v = (src >= 0) ? W[((size_t)k * OO + o) * DIMD + src] : 0.0f;
    Wbf[((size_t)k * OO + o) * KP + d] = f2bf(v);
}

__global__ __launch_bounds__(256, 2)
void gemm_lstm_k(const float* __restrict__ h_pool, const float* __restrict__ c_pool,
                 const float* __restrict__ t_pool, const int* __restrict__ child_idx,
                 const float* __restrict__ bias, const u16* __restrict__ Wbf,
                 const int* __restrict__ hdr, const int* __restrict__ idxbuf,
                 float* __restrict__ out) {
    __shared__ u16 sA[RT * LDSP];

    const int bx = blockIdx.x;
    if (bx >= hdr[24]) return;
    int k = 0;
    #pragma unroll
    for (int j = 1; j < KN; ++j) if (bx >= hdr[16 + j]) k = j;

    const int c0  = blockIdx.y * 64;     // h-col tile base (2 tiles cover 128)
    const int tid = threadIdx.x;

    // ---------- gather x rows into LDS (bf16) ----------
    {
        int r = tid >> 2, q = tid & 3;           // 4 threads per row
        int node = idxbuf[bx * RT + r];
        u16* row = &sA[r * LDSP];
        if (node >= 0) {
            int li = child_idx[2 * node], ri = child_idx[2 * node + 1];
            const float4* hl = (const float4*)(h_pool + (size_t)li * HV);
            const float4* hr = (const float4*)(h_pool + (size_t)ri * HV);
            ushort4* rw  = (ushort4*)row;            // h_l at 0
            ushort4* rw2 = (ushort4*)(row + 128);    // h_r at 128
            #pragma unroll
            for (int i = q; i < 32; i += 4) {
                float4 v = hl[i];
                rw[i] = make_ushort4(f2bf(v.x), f2bf(v.y), f2bf(v.z), f2bf(v.w));
            }
            #pragma unroll
            for (int i = q; i < 32; i += 4) {
                float4 v = hr[i];
                rw2[i] = make_ushort4(f2bf(v.x), f2bf(v.y), f2bf(v.z), f2bf(v.w));
            }
            for (int j = q; j < HT; j += 4) {
                row[256 + j] = f2bf(t_pool[(size_t)li * HT + j]);
                row[273 + j] = f2bf(t_pool[(size_t)ri * HT + j]);
            }
            for (int j = 290 + q; j < KP; j += 4) row[j] = 0;
        } else {
            for (int j = q; j < KP; j += 4) row[j] = 0;
        }
    }
    __syncthreads();

    // ---------- MFMA main loop ----------
    const int wv = tid >> 6, lane = tid & 63;
    const int wr = wv >> 1, wc = wv & 1;         // wave grid 2x2: rows x cols
    const int lo = lane & 15, hi = lane >> 4;

    f32x4 acc[5][2][2];                          // [gate][colfrag][rowfrag]
    #pragma unroll
    for (int g = 0; g < 5; ++g)
        #pragma unroll
        for (int cf = 0; cf < 2; ++cf)
            #pragma unroll
            for (int mr = 0; mr < 2; ++mr)
                acc[g][cf][mr] = (f32x4){0.f, 0.f, 0.f, 0.f};

    const u16* __restrict__ wbase = Wbf + (size_t)k * OO * KP;
    int woffs[5][2];
    #pragma unroll
    for (int g = 0; g < 5; ++g)
        #pragma unroll
        for (int cf = 0; cf < 2; ++cf)
            woffs[g][cf] = (g * 128 + c0 + wc * 32 + cf * 16 + lo) * KP + hi * 8;

    const u16* ap0 = &sA[(wr * 32 + lo) * LDSP + hi * 8];
    const u16* ap1 = ap0 + 16 * LDSP;

    #pragma unroll
    for (int kk = 0; kk < 10; ++kk) {
        const int kb = kk * 32;
        short8v a0 = *(const short8v*)(ap0 + kb);
        short8v a1 = *(const short8v*)(ap1 + kb);
        #pragma unroll
        for (int g = 0; g < 5; ++g) {
            #pragma unroll
            for (int cf = 0; cf < 2; ++cf) {
                short8v bf = *(const short8v*)(wbase + woffs[g][cf] + kb);
                acc[g][cf][0] = __builtin_amdgcn_mfma_f32_16x16x32_bf16(a0, bf, acc[g][cf][0], 0, 0, 0);
                acc[g][cf][1] = __builtin_amdgcn_mfma_f32_16x16x32_bf16(a1, bf, acc[g][cf][1], 0, 0, 0);
            }
        }
    }

    // ---------- fused LSTM epilogue ----------
    const int hc0 = c0 + wc * 32 + lo;
    float bb[5][2];
    #pragma unroll
    for (int g = 0; g < 5; ++g) {
        bb[g][0] = bias[k * OO + g * 128 + hc0];
        bb[g][1] = bias[k * OO + g * 128 + hc0 + 16];
    }

    #pragma unroll
    for (int mr = 0; mr < 2; ++mr) {
        #pragma unroll
        for (int jj = 0; jj < 4; ++jj) {
            int rl = wr * 32 + mr * 16 + hi * 4 + jj;
            int node = idxbuf[bx * RT + rl];
            if (node < 0) continue;
            int li = child_idx[2 * node], ri = child_idx[2 * node + 1];
            const float* clp = c_pool + (size_t)li * HV;
            const float* crp = c_pool + (size_t)ri * HV;
            float* orow = out + (size_t)node * (2 * HV);
            #pragma unroll
            for (int cf = 0; cf < 2; ++cf) {
                int hcol = hc0 + cf * 16;
                float cl = clp[hcol], cr = crp[hcol];
                float gi  = acc[0][cf][mr][jj] + bb[0][cf];
                float gfl = acc[1][cf][mr][jj] + bb[1][cf];
                float gfr = acc[2][cf][mr][jj] + bb[2][cf];
                float gu  = acc[3][cf][mr][jj] + bb[3][cf];
                float go  = acc[4][cf][mr][jj] + bb[4][cf];
                float cc = sigf(gi) * tanhf(gu) + sigf(gfl) * cl + sigf(gfr) * cr;
                float hh = sigf(go) * tanhf(cc);
                orow[hcol]      = hh;
                orow[HV + hcol] = cc;
            }
        }
    }
}

extern "C" void kernel_launch(void* const* d_in, const int* in_sizes, int n_in,
                              void* d_out, int out_size, void* d_ws, size_t ws_size,
                              hipStream_t stream) {
    const float* h_pool      = (const float*)d_in[0];
    const float* c_pool      = (const float*)d_in[1];
    const float* t_pool      = (const float*)d_in[2];
    const int*   child_idx   = (const int*)d_in[3];
    const int*   parent_type = (const int*)d_in[4];
    const float* W           = (const float*)d_in[5];
    const float* bias        = (const float*)d_in[6];
    float* out = (float*)d_out;

    const int N = in_sizes[3] / 2;

    char* ws = (char*)d_ws;
    int* hdr    = (int*)ws;
    int* idxbuf = (int*)(ws + 1024);
    const int idx_count = N + KN * RT;
    size_t woff = 1024 + (((size_t)idx_count * 4 + 255) / 256) * 256;
    u16* Wbf = (u16*)(ws + woff);

    hipMemsetAsync(hdr, 0, 1024, stream);
    hipMemsetAsync(idxbuf, 0xFF, (size_t)idx_count * 4, stream);

    int nb = (N + 255) / 256;
    hist_k<<<nb, 256, 0, stream>>>(parent_type, hdr, N);
    prefix_k<<<1, 64, 0, stream>>>(hdr);
    scatter_k<<<nb, 256, 0, stream>>>(parent_type, hdr, idxbuf, N);
    wconv_k<<<dim3((OO * KP + 255) / 256, KN), 256, 0, stream>>>(W, Wbf);

    int maxblk = (N + RT - 1) / RT + KN;
    gemm_lstm_k<<<dim3(maxblk, 2), 256, 0, stream>>>(
        h_pool, c_pool, t_pool, child_idx, bias, Wbf, hdr, idxbuf, out);
}

// Round 2
// 358.123 us; speedup vs baseline: 1.6174x; 1.6174x over previous
//
#include <hip/hip_runtime.h>
#include <hip/hip_bf16.h>

// Sizes fixed by the reference
#define HV   128
#define HT   17
#define DIMD 290        // 2*(HV+HT)
#define KP   320        // K padded to 10*32 for mfma 16x16x32
#define LDSP 328        // LDS row pitch (bf16 elems) to break bank aliasing
#define OO   640        // 5*HV
#define RT   64         // rows per block
#define KN   8          // number of types

typedef unsigned short u16;
typedef __attribute__((ext_vector_type(8))) short short8v;
typedef __attribute__((ext_vector_type(4))) float f32x4;

__device__ __forceinline__ u16 f2bf(float x) {
    unsigned u = __float_as_uint(x);
    u = (u + 0x7FFFu + ((u >> 16) & 1u)) >> 16;   // RNE
    return (u16)u;
}
__device__ __forceinline__ float sigf(float x) {
    return __builtin_amdgcn_rcpf(1.0f + __expf(-x));
}
__device__ __forceinline__ float tanhfast(float x) {
    // tanh(x) = 1 - 2/(e^{2x}+1); rcp(inf)=0 handles saturation
    return 1.0f - 2.0f * __builtin_amdgcn_rcpf(1.0f + __expf(2.0f * x));
}

// ws header layout (ints): [0..7] counts, [8..15] scatter cursors,
// [16..24] blkStart prefix (blkStart[8] = total row-blocks)

__global__ void hist_k(const int* __restrict__ pt, int* __restrict__ hdr, int N) {
    __shared__ int c[KN];
    if (threadIdx.x < KN) c[threadIdx.x] = 0;
    __syncthreads();
    int n = blockIdx.x * 256 + threadIdx.x;
    if (n < N) atomicAdd(&c[pt[n]], 1);
    __syncthreads();
    if (threadIdx.x < KN && c[threadIdx.x]) atomicAdd(&hdr[threadIdx.x], c[threadIdx.x]);
}

__global__ void prefix_k(int* __restrict__ hdr) {
    if (threadIdx.x == 0 && blockIdx.x == 0) {
        int acc = 0;
        hdr[16] = 0;
        for (int k = 0; k < KN; ++k) {
            acc += (hdr[k] + RT - 1) / RT;
            hdr[17 + k] = acc;
        }
    }
}

__global__ void scatter_k(const int* __restrict__ pt, int* __restrict__ hdr,
                          int* __restrict__ idxbuf, int N) {
    __shared__ int c[KN], base[KN];
    if (threadIdx.x < KN) c[threadIdx.x] = 0;
    __syncthreads();
    int n = blockIdx.x * 256 + threadIdx.x;
    int k = 0, my = 0;
    if (n < N) { k = pt[n]; my = atomicAdd(&c[k], 1); }
    __syncthreads();
    if (threadIdx.x < KN)
        base[threadIdx.x] = c[threadIdx.x] ? atomicAdd(&hdr[8 + threadIdx.x], c[threadIdx.x]) : 0;
    __syncthreads();
    if (n < N) idxbuf[hdr[16 + k] * RT + base[k] + my] = n;
}

// W (K,O,290) fp32 -> Wbf (K,O,320) bf16 with column permutation:
// x' layout = [h_l 0..128 | h_r 128..256 | t_l 256..273 | t_r 273..290 | 0 pad]
__global__ void wconv_k(const float* __restrict__ W, u16* __restrict__ Wbf) {
    int k = blockIdx.y;
    int idx = blockIdx.x * 256 + threadIdx.x;
    if (idx >= OO * KP) return;
    int o = idx / KP, d = idx % KP;
    int src;
    if (d < 256)      src = (d < 128) ? d : d + 17;   // h_l / h_r (orig h_r at 145)
    else if (d < 273) src = d - 128;                  // t_l (orig at 128)
    else if (d < 290) src = d;                        // t_r (orig at 273)
    else              src = -1;                       // pad
    float v = (src >= 0) ? W[((size_t)k * OO + o) * DIMD + src] : 0.0f;
    Wbf[((size_t)k * OO + o) * KP + d] = f2bf(v);
}

// One block: 64 rows x 128 h-cols (all 640 gate outputs). 8 waves, each
// wave owns 64 rows x 16 h-cols (mr=4 row-frags, 5 gates) -> B-frag reuse 4x.
__global__ __launch_bounds__(512, 4)
void gemm_lstm_k(const float* __restrict__ h_pool, const float* __restrict__ c_pool,
                 const float* __restrict__ t_pool, const int* __restrict__ child_idx,
                 const float* __restrict__ bias, const u16* __restrict__ Wbf,
                 const int* __restrict__ hdr, const int* __restrict__ idxbuf,
                 float* __restrict__ out) {
    __shared__ u16 sA[RT * LDSP];
    __shared__ int sNode[RT], sL[RT], sR[RT];

    const int bx = blockIdx.x;
    if (bx >= hdr[24]) return;
    int k = 0;
    #pragma unroll
    for (int j = 1; j < KN; ++j) if (bx >= hdr[16 + j]) k = j;

    const int tid = threadIdx.x;

    // ---------- gather x rows into LDS (bf16), 8 threads per row ----------
    {
        int r = tid >> 3, q = tid & 7;
        int node = idxbuf[bx * RT + r];
        if (q == 0) sNode[r] = node;
        u16* row = &sA[r * LDSP];
        if (node >= 0) {
            int li = child_idx[2 * node], ri = child_idx[2 * node + 1];
            if (q == 0) { sL[r] = li; sR[r] = ri; }
            const float4* hl = (const float4*)(h_pool + (size_t)li * HV);
            const float4* hr = (const float4*)(h_pool + (size_t)ri * HV);
            ushort4* rw  = (ushort4*)row;            // h_l at 0
            ushort4* rw2 = (ushort4*)(row + 128);    // h_r at 128
            #pragma unroll
            for (int i = q; i < 32; i += 8) {
                float4 v = hl[i];
                rw[i] = make_ushort4(f2bf(v.x), f2bf(v.y), f2bf(v.z), f2bf(v.w));
            }
            #pragma unroll
            for (int i = q; i < 32; i += 8) {
                float4 v = hr[i];
                rw2[i] = make_ushort4(f2bf(v.x), f2bf(v.y), f2bf(v.z), f2bf(v.w));
            }
            for (int j = q; j < HT; j += 8) {
                row[256 + j] = f2bf(t_pool[(size_t)li * HT + j]);
                row[273 + j] = f2bf(t_pool[(size_t)ri * HT + j]);
            }
            for (int j = 290 + q; j < KP; j += 8) row[j] = 0;
        } else {
            for (int j = q; j < KP; j += 8) row[j] = 0;
        }
    }
    __syncthreads();

    // ---------- MFMA main loop ----------
    const int wc = tid >> 6, lane = tid & 63;    // 8 waves = 8 col groups of 16
    const int lo = lane & 15, hi = lane >> 4;

    f32x4 acc[5][4];                             // [gate][rowfrag]
    #pragma unroll
    for (int g = 0; g < 5; ++g)
        #pragma unroll
        for (int mr = 0; mr < 4; ++mr)
            acc[g][mr] = (f32x4){0.f, 0.f, 0.f, 0.f};

    const u16* __restrict__ wbase = Wbf + (size_t)k * OO * KP;
    int wo[5];
    #pragma unroll
    for (int g = 0; g < 5; ++g)
        wo[g] = (g * 128 + wc * 16 + lo) * KP + hi * 8;

    const u16* ap = &sA[lo * LDSP + hi * 8];

    #pragma unroll
    for (int kk = 0; kk < 10; ++kk) {
        const int kb = kk * 32;
        short8v a0 = *(const short8v*)(ap + kb);
        short8v a1 = *(const short8v*)(ap + 16 * LDSP + kb);
        short8v a2 = *(const short8v*)(ap + 32 * LDSP + kb);
        short8v a3 = *(const short8v*)(ap + 48 * LDSP + kb);
        #pragma unroll
        for (int g = 0; g < 5; ++g) {
            short8v bf = *(const short8v*)(wbase + wo[g] + kb);
            acc[g][0] = __builtin_amdgcn_mfma_f32_16x16x32_bf16(a0, bf, acc[g][0], 0, 0, 0);
            acc[g][1] = __builtin_amdgcn_mfma_f32_16x16x32_bf16(a1, bf, acc[g][1], 0, 0, 0);
            acc[g][2] = __builtin_amdgcn_mfma_f32_16x16x32_bf16(a2, bf, acc[g][2], 0, 0, 0);
            acc[g][3] = __builtin_amdgcn_mfma_f32_16x16x32_bf16(a3, bf, acc[g][3], 0, 0, 0);
        }
    }

    // ---------- fused LSTM epilogue ----------
    const int hcol = wc * 16 + lo;
    float bb[5];
    #pragma unroll
    for (int g = 0; g < 5; ++g) bb[g] = bias[k * OO + g * 128 + hcol];

    #pragma unroll
    for (int mr = 0; mr < 4; ++mr) {
        #pragma unroll
        for (int jj = 0; jj < 4; ++jj) {
            int rl = mr * 16 + hi * 4 + jj;
            int node = sNode[rl];
            if (node < 0) continue;
            int li = sL[rl], ri = sR[rl];
            float cl = c_pool[(size_t)li * HV + hcol];
            float cr = c_pool[(size_t)ri * HV + hcol];
            float gi  = acc[0][mr][jj] + bb[0];
            float gfl = acc[1][mr][jj] + bb[1];
            float gfr = acc[2][mr][jj] + bb[2];
            float gu  = acc[3][mr][jj] + bb[3];
            float go  = acc[4][mr][jj] + bb[4];
            float cc = sigf(gi) * tanhfast(gu) + sigf(gfl) * cl + sigf(gfr) * cr;
            float hh = sigf(go) * tanhfast(cc);
            float* orow = out + (size_t)node * (2 * HV);
            orow[hcol]      = hh;
            orow[HV + hcol] = cc;
        }
    }
}

extern "C" void kernel_launch(void* const* d_in, const int* in_sizes, int n_in,
                              void* d_out, int out_size, void* d_ws, size_t ws_size,
                              hipStream_t stream) {
    const float* h_pool      = (const float*)d_in[0];
    const float* c_pool      = (const float*)d_in[1];
    const float* t_pool      = (const float*)d_in[2];
    const int*   child_idx   = (const int*)d_in[3];
    const int*   parent_type = (const int*)d_in[4];
    const float* W           = (const float*)d_in[5];
    const float* bias        = (const float*)d_in[6];
    float* out = (float*)d_out;

    const int N = in_sizes[3] / 2;

    char* ws = (char*)d_ws;
    int* hdr    = (int*)ws;
    int* idxbuf = (int*)(ws + 1024);
    const int idx_count = N + KN * RT;
    size_t woff = 1024 + (((size_t)idx_count * 4 + 255) / 256) * 256;
    u16* Wbf = (u16*)(ws + woff);

    hipMemsetAsync(hdr, 0, 1024, stream);
    hipMemsetAsync(idxbuf, 0xFF, (size_t)idx_count * 4, stream);

    int nb = (N + 255) / 256;
    hist_k<<<nb, 256, 0, stream>>>(parent_type, hdr, N);
    prefix_k<<<1, 64, 0, stream>>>(hdr);
    scatter_k<<<nb, 256, 0, stream>>>(parent_type, hdr, idxbuf, N);
    wconv_k<<<dim3((OO * KP + 255) / 256, KN), 256, 0, stream>>>(W, Wbf);

    int maxblk = (N + RT - 1) / RT + KN;
    gemm_lstm_k<<<maxblk, 512, 0, stream>>>(
        h_pool, c_pool, t_pool, child_idx, bias, Wbf, hdr, idxbuf, out);
}